// Round 1
// baseline (246.074 us; speedup 1.0000x reference)
//
#include <hip/hip_runtime.h>
#include <hip/hip_bf16.h>
#include <math.h>

// Problem: topic-verb attention over ragged spans.
//   value = V[verb_ids]             [N, L=8, Dw=300]
//   key   = value @ k_w^T + k_b     [N, L, Dt=256]
//   query = q_w @ topic_emb + q_b   [Dt]
//   scores= (key . query)/16, mask l>=span_len with -inf, softmax over L
//   out   = attn @ value            [N, Dw]
//
// Algebraic collapse: scores[n,l] = (value[n,l] . w + c) / 1, where
//   w = (k_w^T @ query)/16  (300 floats), c = (k_b . query)/16 (scalar).
// So the big tensors key/query never materialize; per span it's a gather +
// 8 dot-300s + softmax-8 + weighted sum. Memory-bound on the V gather.

#define SPAN_L 8
#define DW 300
#define DT 256

// ---------- kernel 1: tiny prep — compute w[300] and c into d_ws ----------
__global__ __launch_bounds__(256) void tva_prep(
    const float* __restrict__ topic_emb,  // [256]
    const float* __restrict__ k_w,        // [256,300]
    const float* __restrict__ k_b,        // [256]
    const float* __restrict__ q_w,        // [256,256]
    const float* __restrict__ q_b,        // [256]
    float* __restrict__ wc)               // out: [301] = w[300], c
{
    __shared__ float te[DT];
    __shared__ float qs[DT];
    const int t = threadIdx.x;  // 256 threads
    te[t] = topic_emb[t];
    __syncthreads();

    // query[t] = q_w[t,:] . topic_emb + q_b[t]
    {
        float acc = q_b[t];
        const float* row = q_w + t * DT;
        #pragma unroll 8
        for (int d = 0; d < DT; ++d) acc += row[d] * te[d];
        qs[t] = acc;
    }
    __syncthreads();

    // w[d] = (sum_t k_w[t,d] * query[t]) / 16
    for (int d = t; d < DW; d += 256) {
        float s = 0.f;
        #pragma unroll 8
        for (int tt = 0; tt < DT; ++tt) s += k_w[tt * DW + d] * qs[tt];
        wc[d] = s * 0.0625f;
    }
    // c = (k_b . query)/16  (softmax-invariant, kept for fidelity)
    if (t == 0) {
        float s = 0.f;
        for (int tt = 0; tt < DT; ++tt) s += k_b[tt] * qs[tt];
        wc[DW] = s * 0.0625f;
    }
}

// ---------- kernel 2: one wave per span ----------
__global__ __launch_bounds__(256) void tva_main(
    const float* __restrict__ V,          // [100000, 300]
    const int*   __restrict__ verb_ids,   // [N, 8]
    const int*   __restrict__ span_len,   // [N]
    const float* __restrict__ wc,         // [301]
    float* __restrict__ out,              // [N, 300]
    int N)
{
    const int wave = threadIdx.x >> 6;
    const int lane = threadIdx.x & 63;
    const int n = blockIdx.x * 4 + wave;
    if (n >= N) return;

    // 300 floats = 75 float4: lane covers chunk `lane`, lanes 0..10 also 64+lane.
    const bool tail = (lane < 11);
    const float4* w4 = (const float4*)wc;
    const float4 wv0 = w4[lane];
    const float4 wv1 = tail ? w4[64 + lane] : make_float4(0.f, 0.f, 0.f, 0.f);
    const float  c   = wc[DW];

    const int len = span_len[n];            // wave-uniform (per-span)

    // Issue ALL gather loads first so the global_load_dwordx4 overlap.
    float4 v0[SPAN_L], v1[SPAN_L];
    #pragma unroll
    for (int l = 0; l < SPAN_L; ++l) {
        if (l < len) {
            const int row = verb_ids[n * SPAN_L + l];
            const float4* vr = (const float4*)(V + (long)row * DW);
            v0[l] = vr[lane];
            v1[l] = tail ? vr[64 + lane] : make_float4(0.f, 0.f, 0.f, 0.f);
        } else {
            v0[l] = make_float4(0.f, 0.f, 0.f, 0.f);
            v1[l] = make_float4(0.f, 0.f, 0.f, 0.f);
        }
    }

    // Per-l partial dot, then 64-lane butterfly reduce (result in all lanes).
    float s[SPAN_L];
    #pragma unroll
    for (int l = 0; l < SPAN_L; ++l) {
        float p = v0[l].x * wv0.x + v0[l].y * wv0.y + v0[l].z * wv0.z + v0[l].w * wv0.w
                + v1[l].x * wv1.x + v1[l].y * wv1.y + v1[l].z * wv1.z + v1[l].w * wv1.w;
        #pragma unroll
        for (int m = 1; m < 64; m <<= 1) p += __shfl_xor(p, m, 64);
        s[l] = (l < len) ? (p + c) : -INFINITY;
    }

    // Softmax over the (<=8) scores; every lane has all of them.
    float mx = s[0];
    #pragma unroll
    for (int l = 1; l < SPAN_L; ++l) mx = fmaxf(mx, s[l]);
    float e[SPAN_L];
    float denom = 0.f;
    #pragma unroll
    for (int l = 0; l < SPAN_L; ++l) { e[l] = __expf(s[l] - mx); denom += e[l]; }
    const float inv = 1.f / denom;

    // Weighted sum of the already-resident rows. Masked l have e=0 and v=0.
    float4 a0 = make_float4(0.f, 0.f, 0.f, 0.f);
    float4 a1 = make_float4(0.f, 0.f, 0.f, 0.f);
    #pragma unroll
    for (int l = 0; l < SPAN_L; ++l) {
        const float al = e[l] * inv;
        a0.x += al * v0[l].x; a0.y += al * v0[l].y; a0.z += al * v0[l].z; a0.w += al * v0[l].w;
        a1.x += al * v1[l].x; a1.y += al * v1[l].y; a1.z += al * v1[l].z; a1.w += al * v1[l].w;
    }

    float4* o4 = (float4*)(out + (long)n * DW);
    o4[lane] = a0;
    if (tail) o4[64 + lane] = a1;
}

extern "C" void kernel_launch(void* const* d_in, const int* in_sizes, int n_in,
                              void* d_out, int out_size, void* d_ws, size_t ws_size,
                              hipStream_t stream) {
    const float* topic_emb = (const float*)d_in[0];
    const int*   verb_ids  = (const int*)  d_in[1];
    const int*   span_len  = (const int*)  d_in[2];
    const float* V         = (const float*)d_in[3];
    const float* k_w       = (const float*)d_in[4];
    const float* k_b       = (const float*)d_in[5];
    const float* q_w       = (const float*)d_in[6];
    const float* q_b       = (const float*)d_in[7];
    float* out = (float*)d_out;
    float* wc  = (float*)d_ws;   // 301 floats of scratch

    const int N = in_sizes[2];   // 16384 spans

    tva_prep<<<1, 256, 0, stream>>>(topic_emb, k_w, k_b, q_w, q_b, wc);
    tva_main<<<(N + 3) / 4, 256, 0, stream>>>(V, verb_ids, span_len, wc, out, N);
}

// Round 2
// 198.302 us; speedup vs baseline: 1.2409x; 1.2409x over previous
//
#include <hip/hip_runtime.h>
#include <hip/hip_bf16.h>
#include <math.h>

// Topic-verb attention over ragged spans — algebraic collapse:
//   scores[n,l] = (value[n,l] . w + c),  w = (k_w^T @ query)/16, c = (k_b.query)/16
//   query = q_w @ topic_emb + q_b
// Per span: gather 8 rows of V, dot each with w, softmax(<=8), weighted sum.
// Memory-bound on the V gather (~157 MB logical, V=120MB fits L3).
//
// R1: prep parallelized across the chip (was 1 block = 1 CU doing 550KB of
// weight reads, ~12-15us). Now: prep_q (32 blocks, coalesced q_w rows +
// butterfly) -> prep_w (76 blocks, 4 outputs each). tva_main gets
// __launch_bounds__(256,4) to guarantee <=128 VGPR / 16 waves/CU.

#define SPAN_L 8
#define DW 300
#define DT 256
#define Q_OFF 320   // query[256] lives at wc[320..575]

__device__ __forceinline__ float wave_reduce(float p) {
    #pragma unroll
    for (int m = 1; m < 64; m <<= 1) p += __shfl_xor(p, m, 64);
    return p;
}

// ---------- prep 1: query[r] = q_w[r,:] . topic_emb + q_b[r] ----------
// 32 blocks x 256 threads; each wave computes 2 rows (coalesced float4 row read).
__global__ __launch_bounds__(256) void tva_prep_q(
    const float* __restrict__ topic_emb,
    const float* __restrict__ q_w,
    const float* __restrict__ q_b,
    float* __restrict__ wc)
{
    const int wave = threadIdx.x >> 6;
    const int lane = threadIdx.x & 63;
    const float4 te4 = ((const float4*)topic_emb)[lane];   // 256 floats = 64 float4
    const int gw = blockIdx.x * 4 + wave;                  // 0..127
    #pragma unroll
    for (int j = 0; j < 2; ++j) {
        const int r = gw * 2 + j;                          // 0..255
        const float4 qr = ((const float4*)(q_w + r * DT))[lane];
        float p = qr.x * te4.x + qr.y * te4.y + qr.z * te4.z + qr.w * te4.w;
        p = wave_reduce(p);
        if (lane == 0) wc[Q_OFF + r] = p + q_b[r];
    }
}

// ---------- prep 2: w[d] = (sum_t k_w[t,d]*query[t])/16 ; c = (k_b.query)/16 ----
// 76 blocks: blocks 0..74 compute 4 d's each (300 total); block 75 computes c.
__global__ __launch_bounds__(256) void tva_prep_w(
    const float* __restrict__ k_w,
    const float* __restrict__ k_b,
    float* __restrict__ wc)
{
    __shared__ float part[4][4];
    const int b = blockIdx.x;
    const int tid = threadIdx.x;
    const int wave = tid >> 6;
    const int lane = tid & 63;

    if (b == 75) {
        if (wave == 0) {
            float p = 0.f;
            #pragma unroll
            for (int j = 0; j < 4; ++j) {
                const int t = lane + 64 * j;
                p += k_b[t] * wc[Q_OFF + t];
            }
            p = wave_reduce(p);
            if (lane == 0) wc[DW] = p * 0.0625f;
        }
        return;
    }

    const int d_off = tid & 3;           // 0..3
    const int t0 = tid >> 2;             // 0..63
    const int d = 4 * b + d_off;
    float p = 0.f;
    #pragma unroll
    for (int j = 0; j < 4; ++j) {
        const int t = t0 + 64 * j;
        p += k_w[t * DW + d] * wc[Q_OFF + t];
    }
    // reduce across the 16 t-positions within the wave (keep d_off lanes apart)
    #pragma unroll
    for (int m = 4; m < 64; m <<= 1) p += __shfl_xor(p, m, 64);
    if (lane < 4) part[wave][lane] = p;
    __syncthreads();
    if (tid < 4)
        wc[4 * b + tid] = (part[0][tid] + part[1][tid] + part[2][tid] + part[3][tid]) * 0.0625f;
}

// ---------- main: one wave per span ----------
__global__ __launch_bounds__(256, 4) void tva_main(
    const float* __restrict__ V,          // [100000, 300]
    const int*   __restrict__ verb_ids,   // [N, 8]
    const int*   __restrict__ span_len,   // [N]
    const float* __restrict__ wc,         // [301] (+query)
    float* __restrict__ out,              // [N, 300]
    int N)
{
    const int wave = threadIdx.x >> 6;
    const int lane = threadIdx.x & 63;
    const int n = blockIdx.x * 4 + wave;
    if (n >= N) return;

    const bool tail = (lane < 11);        // 300 floats = 75 float4 = 64 + 11
    const float4* w4 = (const float4*)wc;
    const float4 wv0 = w4[lane];
    const float4 wv1 = tail ? w4[64 + lane] : make_float4(0.f, 0.f, 0.f, 0.f);
    const float  c   = wc[DW];

    const int len = span_len[n];          // wave-uniform

    // Issue all gather loads first so the global_load_dwordx4 overlap.
    float4 v0[SPAN_L], v1[SPAN_L];
    #pragma unroll
    for (int l = 0; l < SPAN_L; ++l) {
        if (l < len) {
            const int row = verb_ids[n * SPAN_L + l];
            const float4* vr = (const float4*)(V + (long)row * DW);
            v0[l] = vr[lane];
            v1[l] = tail ? vr[64 + lane] : make_float4(0.f, 0.f, 0.f, 0.f);
        } else {
            v0[l] = make_float4(0.f, 0.f, 0.f, 0.f);
            v1[l] = make_float4(0.f, 0.f, 0.f, 0.f);
        }
    }

    float s[SPAN_L];
    #pragma unroll
    for (int l = 0; l < SPAN_L; ++l) {
        float p = v0[l].x * wv0.x + v0[l].y * wv0.y + v0[l].z * wv0.z + v0[l].w * wv0.w
                + v1[l].x * wv1.x + v1[l].y * wv1.y + v1[l].z * wv1.z + v1[l].w * wv1.w;
        p = wave_reduce(p);
        s[l] = (l < len) ? (p + c) : -INFINITY;
    }

    float mx = s[0];
    #pragma unroll
    for (int l = 1; l < SPAN_L; ++l) mx = fmaxf(mx, s[l]);
    float e[SPAN_L];
    float denom = 0.f;
    #pragma unroll
    for (int l = 0; l < SPAN_L; ++l) { e[l] = __expf(s[l] - mx); denom += e[l]; }
    const float inv = 1.f / denom;

    float4 a0 = make_float4(0.f, 0.f, 0.f, 0.f);
    float4 a1 = make_float4(0.f, 0.f, 0.f, 0.f);
    #pragma unroll
    for (int l = 0; l < SPAN_L; ++l) {
        const float al = e[l] * inv;
        a0.x += al * v0[l].x; a0.y += al * v0[l].y; a0.z += al * v0[l].z; a0.w += al * v0[l].w;
        a1.x += al * v1[l].x; a1.y += al * v1[l].y; a1.z += al * v1[l].z; a1.w += al * v1[l].w;
    }

    float4* o4 = (float4*)(out + (long)n * DW);
    o4[lane] = a0;
    if (tail) o4[64 + lane] = a1;
}

extern "C" void kernel_launch(void* const* d_in, const int* in_sizes, int n_in,
                              void* d_out, int out_size, void* d_ws, size_t ws_size,
                              hipStream_t stream) {
    const float* topic_emb = (const float*)d_in[0];
    const int*   verb_ids  = (const int*)  d_in[1];
    const int*   span_len  = (const int*)  d_in[2];
    const float* V         = (const float*)d_in[3];
    const float* k_w       = (const float*)d_in[4];
    const float* k_b       = (const float*)d_in[5];
    const float* q_w       = (const float*)d_in[6];
    const float* q_b       = (const float*)d_in[7];
    float* out = (float*)d_out;
    float* wc  = (float*)d_ws;   // [0..299]=w, [300]=c, [320..575]=query

    const int N = in_sizes[2];   // 16384 spans

    tva_prep_q<<<32, 256, 0, stream>>>(topic_emb, q_w, q_b, wc);
    tva_prep_w<<<76, 256, 0, stream>>>(k_w, k_b, wc);
    tva_main<<<(N + 3) / 4, 256, 0, stream>>>(V, verb_ids, span_len, wc, out, N);
}

// Round 3
// 197.342 us; speedup vs baseline: 1.2469x; 1.0049x over previous
//
#include <hip/hip_runtime.h>
#include <hip/hip_bf16.h>
#include <math.h>

// Topic-verb attention over ragged spans — algebraic collapse:
//   scores[n,l] = value[n,l] . w + c,  w = (k_w^T @ query)/16, c = (k_b.query)/16
//   query = q_w @ topic_emb + q_b
// Per span: gather <=8 rows of V, dot each with w, softmax, weighted sum.
// Memory-bound on the V gather (~88 MB logical; V=120 MB is L3-resident).
//
// R2: (a) nontemporal float4 stores for `out` (write-once; keep V hot in L3),
//     (b) verb_ids loaded as 2x int4 instead of 8 scalar loads.
// Measured floor context: harness reset (480 MB ws fill + input restore)
// accounts for ~165 us of dur_us; controllable kernel share ~33 us.

#define SPAN_L 8
#define DW 300
#define DT 256
#define Q_OFF 320   // query[256] lives at wc[320..575]

typedef float f32x4 __attribute__((ext_vector_type(4)));

__device__ __forceinline__ float wave_reduce(float p) {
    #pragma unroll
    for (int m = 1; m < 64; m <<= 1) p += __shfl_xor(p, m, 64);
    return p;
}

// ---------- prep 1: query[r] = q_w[r,:] . topic_emb + q_b[r] ----------
__global__ __launch_bounds__(256) void tva_prep_q(
    const float* __restrict__ topic_emb,
    const float* __restrict__ q_w,
    const float* __restrict__ q_b,
    float* __restrict__ wc)
{
    const int wave = threadIdx.x >> 6;
    const int lane = threadIdx.x & 63;
    const float4 te4 = ((const float4*)topic_emb)[lane];   // 256 floats = 64 float4
    const int gw = blockIdx.x * 4 + wave;                  // 0..127
    #pragma unroll
    for (int j = 0; j < 2; ++j) {
        const int r = gw * 2 + j;                          // 0..255
        const float4 qr = ((const float4*)(q_w + r * DT))[lane];
        float p = qr.x * te4.x + qr.y * te4.y + qr.z * te4.z + qr.w * te4.w;
        p = wave_reduce(p);
        if (lane == 0) wc[Q_OFF + r] = p + q_b[r];
    }
}

// ---------- prep 2: w[d] = (sum_t k_w[t,d]*query[t])/16 ; c = (k_b.query)/16 ----
__global__ __launch_bounds__(256) void tva_prep_w(
    const float* __restrict__ k_w,
    const float* __restrict__ k_b,
    float* __restrict__ wc)
{
    __shared__ float part[4][4];
    const int b = blockIdx.x;
    const int tid = threadIdx.x;
    const int wave = tid >> 6;
    const int lane = tid & 63;

    if (b == 75) {
        if (wave == 0) {
            float p = 0.f;
            #pragma unroll
            for (int j = 0; j < 4; ++j) {
                const int t = lane + 64 * j;
                p += k_b[t] * wc[Q_OFF + t];
            }
            p = wave_reduce(p);
            if (lane == 0) wc[DW] = p * 0.0625f;
        }
        return;
    }

    const int d_off = tid & 3;           // 0..3
    const int t0 = tid >> 2;             // 0..63
    const int d = 4 * b + d_off;
    float p = 0.f;
    #pragma unroll
    for (int j = 0; j < 4; ++j) {
        const int t = t0 + 64 * j;
        p += k_w[t * DW + d] * wc[Q_OFF + t];
    }
    #pragma unroll
    for (int m = 4; m < 64; m <<= 1) p += __shfl_xor(p, m, 64);
    if (lane < 4) part[wave][lane] = p;
    __syncthreads();
    if (tid < 4)
        wc[4 * b + tid] = (part[0][tid] + part[1][tid] + part[2][tid] + part[3][tid]) * 0.0625f;
}

// ---------- main: one wave per span ----------
__global__ __launch_bounds__(256, 4) void tva_main(
    const float* __restrict__ V,          // [100000, 300]
    const int*   __restrict__ verb_ids,   // [N, 8]
    const int*   __restrict__ span_len,   // [N]
    const float* __restrict__ wc,         // [301] (+query at 320)
    float* __restrict__ out,              // [N, 300]
    int N)
{
    const int wave = threadIdx.x >> 6;
    const int lane = threadIdx.x & 63;
    const int n = blockIdx.x * 4 + wave;
    if (n >= N) return;

    const bool tail = (lane < 11);        // 300 floats = 75 float4 = 64 + 11
    const float4* w4 = (const float4*)wc;
    const float4 wv0 = w4[lane];
    const float4 wv1 = tail ? w4[64 + lane] : make_float4(0.f, 0.f, 0.f, 0.f);
    const float  c   = wc[DW];

    const int len = span_len[n];          // wave-uniform

    // ids as two int4 (wave-uniform addresses -> 2 dwordx4 instead of 8 dword)
    const int4* ids4 = (const int4*)(verb_ids + n * SPAN_L);
    const int4 ia = ids4[0];
    const int4 ib = ids4[1];
    int rows[SPAN_L] = {ia.x, ia.y, ia.z, ia.w, ib.x, ib.y, ib.z, ib.w};

    // Issue all gather loads first so the global_load_dwordx4 overlap.
    float4 v0[SPAN_L], v1[SPAN_L];
    #pragma unroll
    for (int l = 0; l < SPAN_L; ++l) {
        if (l < len) {
            const float4* vr = (const float4*)(V + (long)rows[l] * DW);
            v0[l] = vr[lane];
            v1[l] = tail ? vr[64 + lane] : make_float4(0.f, 0.f, 0.f, 0.f);
        } else {
            v0[l] = make_float4(0.f, 0.f, 0.f, 0.f);
            v1[l] = make_float4(0.f, 0.f, 0.f, 0.f);
        }
    }

    float s[SPAN_L];
    #pragma unroll
    for (int l = 0; l < SPAN_L; ++l) {
        float p = v0[l].x * wv0.x + v0[l].y * wv0.y + v0[l].z * wv0.z + v0[l].w * wv0.w
                + v1[l].x * wv1.x + v1[l].y * wv1.y + v1[l].z * wv1.z + v1[l].w * wv1.w;
        p = wave_reduce(p);
        s[l] = (l < len) ? (p + c) : -INFINITY;
    }

    float mx = s[0];
    #pragma unroll
    for (int l = 1; l < SPAN_L; ++l) mx = fmaxf(mx, s[l]);
    float e[SPAN_L];
    float denom = 0.f;
    #pragma unroll
    for (int l = 0; l < SPAN_L; ++l) { e[l] = __expf(s[l] - mx); denom += e[l]; }
    const float inv = 1.f / denom;

    f32x4 a0 = {0.f, 0.f, 0.f, 0.f};
    f32x4 a1 = {0.f, 0.f, 0.f, 0.f};
    #pragma unroll
    for (int l = 0; l < SPAN_L; ++l) {
        const float al = e[l] * inv;
        a0.x += al * v0[l].x; a0.y += al * v0[l].y; a0.z += al * v0[l].z; a0.w += al * v0[l].w;
        a1.x += al * v1[l].x; a1.y += al * v1[l].y; a1.z += al * v1[l].z; a1.w += al * v1[l].w;
    }

    // Nontemporal stores: out is write-once, never re-read -> don't evict V from L2/L3.
    f32x4* o4 = (f32x4*)(out + (long)n * DW);
    __builtin_nontemporal_store(a0, o4 + lane);
    if (tail) __builtin_nontemporal_store(a1, o4 + 64 + lane);
}

extern "C" void kernel_launch(void* const* d_in, const int* in_sizes, int n_in,
                              void* d_out, int out_size, void* d_ws, size_t ws_size,
                              hipStream_t stream) {
    const float* topic_emb = (const float*)d_in[0];
    const int*   verb_ids  = (const int*)  d_in[1];
    const int*   span_len  = (const int*)  d_in[2];
    const float* V         = (const float*)d_in[3];
    const float* k_w       = (const float*)d_in[4];
    const float* k_b       = (const float*)d_in[5];
    const float* q_w       = (const float*)d_in[6];
    const float* q_b       = (const float*)d_in[7];
    float* out = (float*)d_out;
    float* wc  = (float*)d_ws;   // [0..299]=w, [300]=c, [320..575]=query

    const int N = in_sizes[2];   // 16384 spans

    tva_prep_q<<<32, 256, 0, stream>>>(topic_emb, q_w, q_b, wc);
    tva_prep_w<<<76, 256, 0, stream>>>(k_w, k_b, wc);
    tva_main<<<(N + 3) / 4, 256, 0, stream>>>(V, verb_ids, span_len, wc, out, N);
}